// Round 16
// baseline (552.516 us; speedup 1.0000x reference)
//
#include <hip/hip_runtime.h>
#include <math.h>

#define B_   8
#define S_   1024
#define SR_  256
#define SN_  1024
#define D1_  768
#define D2_  512
#define D3_  768
#define MVH_ 256
#define H_   12
#define HD_  64
#define MLP_ 3072

typedef __attribute__((ext_vector_type(8))) short bf16x8;
typedef __attribute__((ext_vector_type(4))) float f32x4;

__device__ inline ushort f2bf(float f) {
  uint u = __float_as_uint(f);
  uint r = (u + 0x7fffu + ((u >> 16) & 1u)) >> 16;
  return (ushort)r;
}
__device__ inline float b2f(ushort u) { return __uint_as_float(((uint)u) << 16); }

__device__ inline void gload16(const void* g, void* l) {
  __builtin_amdgcn_global_load_lds(
      (const __attribute__((address_space(1))) void*)g,
      (__attribute__((address_space(3))) void*)l, 16, 0, 0);
}

// bijective XCD-aware work remap (m204)
__device__ inline int xcd_swz(int lin, int n) {
  int xcd = lin & 7, idx = lin >> 3;
  int q = n >> 3, r = n & 7;
  return (xcd < r ? xcd * (q + 1) : r * (q + 1) + (xcd - r) * q) + idx;
}

// ---------------- LayerNorm (dual bf16 out) ----------------
__global__ __launch_bounds__(256) void ln_dual_b(const float* __restrict__ x,
    const float* __restrict__ w1, const float* __restrict__ w2,
    ushort* __restrict__ o1, ushort* __restrict__ o2, int D) {
  int row = blockIdx.x;
  const float* xr = x + (size_t)row * D;
  int tid = threadIdx.x;
  float s = 0.f, ss = 0.f;
  for (int i = tid; i < D; i += 256) { float v = xr[i]; s += v; ss += v * v; }
  __shared__ float rs[256];
  __shared__ float rq[256];
  rs[tid] = s; rq[tid] = ss;
  __syncthreads();
  for (int off = 128; off > 0; off >>= 1) {
    if (tid < off) { rs[tid] += rs[tid + off]; rq[tid] += rq[tid + off]; }
    __syncthreads();
  }
  float mu  = rs[0] / (float)D;
  float var = rq[0] / (float)D - mu * mu;
  float inv = rsqrtf(var + 1e-6f);
  for (int i = tid; i < D; i += 256) {
    float v = (xr[i] - mu) * inv;
    o1[(size_t)row * D + i] = f2bf(v * w1[i]);
    o2[(size_t)row * D + i] = f2bf(v * w2[i]);
  }
}

// ---------------- LayerNorm (bf16 out, single) ----------------
__global__ __launch_bounds__(256) void ln_b(const float* __restrict__ x,
    const float* __restrict__ w, ushort* __restrict__ o, int D) {
  int row = blockIdx.x;
  const float* xr = x + (size_t)row * D;
  int tid = threadIdx.x;
  float s = 0.f, ss = 0.f;
  for (int i = tid; i < D; i += 256) { float v = xr[i]; s += v; ss += v * v; }
  __shared__ float rs[256];
  __shared__ float rq[256];
  rs[tid] = s; rq[tid] = ss;
  __syncthreads();
  for (int off = 128; off > 0; off >>= 1) {
    if (tid < off) { rs[tid] += rs[tid + off]; rq[tid] += rq[tid + off]; }
    __syncthreads();
  }
  float mu  = rs[0] / (float)D;
  float var = rq[0] / (float)D - mu * mu;
  float inv = rsqrtf(var + 1e-6f);
  for (int i = tid; i < D; i += 256) {
    float v = (xr[i] - mu) * inv;
    o[(size_t)row * D + i] = f2bf(v * w[i]);
  }
}

// ---------------- transpose fp32 -> bf16 ----------------
__global__ __launch_bounds__(256) void trans_f2b(const float* __restrict__ in,
    ushort* __restrict__ out, int R, int C, long strideEl) {
  __shared__ float tile[32][33];
  int bb = blockIdx.z;
  const float* ib = in + (size_t)bb * strideEl;
  ushort* ob = out + (size_t)bb * strideEl;
  int c0 = blockIdx.x << 5, r0 = blockIdx.y << 5;
  int tx = threadIdx.x & 31, ty = threadIdx.x >> 5;
#pragma unroll
  for (int i = 0; i < 4; ++i)
    tile[ty + 8 * i][tx] = ib[(size_t)(r0 + ty + 8 * i) * C + c0 + tx];
  __syncthreads();
#pragma unroll
  for (int i = 0; i < 4; ++i)
    ob[(size_t)(c0 + ty + 8 * i) * R + r0 + tx] = f2bf(tile[tx][ty + 8 * i]);
}

// ---------------- transpose bf16 -> bf16 ----------------
__global__ __launch_bounds__(256) void trans_b2b(const ushort* __restrict__ in,
    ushort* __restrict__ out, int R, int C, long strideEl) {
  __shared__ ushort tile[32][33];
  int bb = blockIdx.z;
  const ushort* ib = in + (size_t)bb * strideEl;
  ushort* ob = out + (size_t)bb * strideEl;
  int c0 = blockIdx.x << 5, r0 = blockIdx.y << 5;
  int tx = threadIdx.x & 31, ty = threadIdx.x >> 5;
#pragma unroll
  for (int i = 0; i < 4; ++i)
    tile[ty + 8 * i][tx] = ib[(size_t)(r0 + ty + 8 * i) * C + c0 + tx];
  __syncthreads();
#pragma unroll
  for (int i = 0; i < 4; ++i)
    ob[(size_t)(c0 + ty + 8 * i) * R + r0 + tx] = tile[tx][ty + 8 * i];
}

// ---------------- multi-tensor fp32 -> bf16 weight conversion ----------------
struct ConvTab {
  const float* src[28];
  int off[28];
  int cum[29];
};
__global__ __launch_bounds__(256) void multi_f2b(ConvTab t, ushort* __restrict__ wb,
                                                 int total4) {
  int i = blockIdx.x * 256 + threadIdx.x;
  if (i >= total4) return;
  int ti = 0;
  while (t.cum[ti + 1] <= i) ++ti;
  int j = i - t.cum[ti];
  float4 v = ((const float4*)t.src[ti])[j];
  ushort4 o;
  o.x = f2bf(v.x); o.y = f2bf(v.y); o.z = f2bf(v.z); o.w = f2bf(v.w);
  ((ushort4*)(wb + t.off[ti]))[j] = o;
}

// ---------------- RoPE cos/sin tables ----------------
__global__ __launch_bounds__(256) void rope_tab(const float* __restrict__ fq,
    const float* __restrict__ fk, float* __restrict__ ctq, float* __restrict__ stq,
    float* __restrict__ ctk, float* __restrict__ stk, int n) {
  int i = blockIdx.x * 256 + threadIdx.x;
  if (i >= n) return;
  float a = fq[i]; ctq[i] = cosf(a); stq[i] = sinf(a);
  float c = fk[i]; ctk[i] = cosf(c); stk[i] = sinf(c);
}

// ---- shared BK=64 GEMM core body ----
#define GEMM_BODY(Ab, Bb, STORE)                                                     \
  __shared__ ushort As[128 * 64];                                                    \
  __shared__ ushort Bs[128 * 64];                                                    \
  int tid = threadIdx.x;                                                             \
  int lane = tid & 63, wid = tid >> 6;                                               \
  int m0 = by << 7, n0 = bx << 7;                                                    \
  int wm = (wid >> 1) << 6, wn = (wid & 1) << 6;                                     \
  f32x4 acc[4][4];                                                                   \
  _Pragma("unroll")                                                                  \
  for (int i = 0; i < 4; ++i)                                                        \
    _Pragma("unroll")                                                                \
    for (int j = 0; j < 4; ++j) acc[i][j] = (f32x4){0.f, 0.f, 0.f, 0.f};             \
  char* asb = (char*)As;                                                             \
  char* bsb = (char*)Bs;                                                             \
  int srow = lane >> 3;                                                              \
  int skb  = (lane & 7) << 4;                                                        \
  for (int k0 = 0; k0 < K; k0 += 64) {                                               \
    __syncthreads();                                                                 \
    _Pragma("unroll")                                                                \
    for (int i = 0; i < 4; ++i) {                                                    \
      int rr = wid * 32 + i * 8;                                                     \
      gload16((const char*)Ab + ((size_t)(m0 + rr + srow) * K + k0) * 2 + skb,       \
              asb + rr * 128);                                                       \
      gload16((const char*)Bb + ((size_t)(n0 + rr + srow) * K + k0) * 2 + skb,       \
              bsb + rr * 128);                                                       \
    }                                                                                \
    __syncthreads();                                                                 \
    bf16x8 af[2][4], bf[2][4];                                                       \
    _Pragma("unroll")                                                                \
    for (int h = 0; h < 2; ++h) {                                                    \
      _Pragma("unroll")                                                              \
      for (int m = 0; m < 4; ++m)                                                    \
        af[h][m] = *(bf16x8*)&As[(wm + m * 16 + (lane & 15)) * 64 + h * 32 +         \
                                 ((lane >> 4) << 3)];                                \
      _Pragma("unroll")                                                              \
      for (int n = 0; n < 4; ++n)                                                    \
        bf[h][n] = *(bf16x8*)&Bs[(wn + n * 16 + (lane & 15)) * 64 + h * 32 +         \
                                 ((lane >> 4) << 3)];                                \
    }                                                                                \
    __builtin_amdgcn_s_setprio(1);                                                   \
    _Pragma("unroll")                                                                \
    for (int h = 0; h < 2; ++h)                                                      \
      _Pragma("unroll")                                                              \
      for (int m = 0; m < 4; ++m)                                                    \
        _Pragma("unroll")                                                            \
        for (int n = 0; n < 4; ++n)                                                  \
          acc[m][n] = __builtin_amdgcn_mfma_f32_16x16x32_bf16(af[h][m], bf[h][n],    \
                                                              acc[m][n], 0, 0, 0);   \
    __builtin_amdgcn_s_setprio(0);                                                   \
  }                                                                                  \
  int cr = (lane >> 4) << 2, cc = lane & 15;                                         \
  _Pragma("unroll")                                                                  \
  for (int m = 0; m < 4; ++m)                                                        \
    _Pragma("unroll")                                                                \
    for (int n = 0; n < 4; ++n) {                                                    \
      _Pragma("unroll")                                                              \
      for (int r = 0; r < 4; ++r) {                                                  \
        int row = m0 + wm + m * 16 + cr + r;                                         \
        int col = n0 + wn + n * 16 + cc;                                             \
        float v = acc[m][n][r];                                                      \
        STORE;                                                                       \
      }                                                                              \
    }

// ---------------- bf16 MFMA GEMM (strided batch): C_b = A_b @ B_b^T ----------------
template <int EPI>
__global__ __launch_bounds__(256) void gemm_bf16(const ushort* __restrict__ A, long sA,
    const ushort* __restrict__ Bm, long sB, const float* __restrict__ R,
    void* __restrict__ Cout, long sC, int M, int N, int K) {
  int gx = gridDim.x, gy = gridDim.y;
  int nwg = gx * gy * gridDim.z;
  int lin = ((int)blockIdx.z * gy + (int)blockIdx.y) * gx + (int)blockIdx.x;
  lin = xcd_swz(lin, nwg);
  int bx = lin % gx, tt = lin / gx;
  int by = tt % gy, bb = tt / gy;
  const ushort* Ab = A + (size_t)bb * sA;
  const ushort* Bb = Bm + (size_t)bb * sB;
  GEMM_BODY(Ab, Bb,
    if (EPI == 0) {
      ((ushort*)Cout)[(size_t)bb * sC + (size_t)row * N + col] = f2bf(v);
    } else if (EPI == 1) {
      ((float*)Cout)[(size_t)row * N + col] = v + R[(size_t)row * N + col];
    } else {
      float y = 0.7978845608f * (v + 0.044715f * v * v * v);
      float sg = 1.0f / (1.0f + __expf(-2.0f * y));
      ((ushort*)Cout)[(size_t)row * N + col] = f2bf(v * sg);
    })
}

// ---------------- grouped bf16 MFMA GEMM ----------------
struct GrpTab {
  const ushort* A[32];
  const ushort* Bm[32];
  ushort* C[32];
};
__global__ __launch_bounds__(256) void gemm_grp(GrpTab t, int M, int N, int K) {
  int gx = gridDim.x, gy = gridDim.y;
  int nwg = gx * gy * gridDim.z;
  int lin = ((int)blockIdx.z * gy + (int)blockIdx.y) * gx + (int)blockIdx.x;
  lin = xcd_swz(lin, nwg);
  int bx = lin % gx, tt = lin / gx;
  int by = tt % gy, zz = tt / gy;
  const ushort* Ab = t.A[zz];
  const ushort* Bb = t.Bm[zz];
  ushort* Cb = t.C[zz];
  GEMM_BODY(Ab, Bb, Cb[(size_t)row * N + col] = f2bf(v))
}

// ---------------- reparameterization (bf16 in/out) ----------------
__global__ __launch_bounds__(256) void z_combine_b(const ushort* __restrict__ mean,
    const ushort* __restrict__ var, const float* __restrict__ eps,
    const float* __restrict__ dirty, const float* __restrict__ e2de_p,
    ushort* __restrict__ zout, int total, int perBatch) {
  int i = blockIdx.x * 256 + threadIdx.x;
  if (i >= total) return;
  float e = e2de_p[0];
  float v = b2f(mean[i]) +
            (e * eps[i] + (1.0f - e) * dirty[i % perBatch]) * expf(0.5f * b2f(var[i]));
  zout[i] = f2bf(v);
}

// ---------------- fused head pack + RoPE (q / k / v sections) ----------------
__global__ __launch_bounds__(256) void pack_all(
    const ushort* __restrict__ qzf, const ushort* __restrict__ qrf,
    const float* __restrict__ ctq, const float* __restrict__ stq, ushort* __restrict__ qp,
    const ushort* __restrict__ kzf, const ushort* __restrict__ krf,
    const float* __restrict__ ctk, const float* __restrict__ stk, ushort* __restrict__ kp,
    const ushort* __restrict__ vzf, ushort* __restrict__ vp, int nblk) {
  int sec = blockIdx.x / nblk;
  int blk = blockIdx.x - sec * nblk;
  int i8 = blk * 256 + threadIdx.x;
  int i = i8 << 3;
  int d0 = i & 63;
  int s = (i >> 6) & (S_ - 1);
  int bh = i >> 16;
  int b = bh / H_, h = bh % H_;
  if (sec == 2) {
    bf16x8 v = *(const bf16x8*)(vzf + ((size_t)(b * S_ + s)) * D3_ + h * 64 + d0);
    *(bf16x8*)(vp + i) = v;
    return;
  }
  const ushort* zf = (sec == 0) ? qzf : kzf;
  const ushort* rf = (sec == 0) ? qrf : krf;
  const float* ct = (sec == 0) ? ctq : ctk;
  const float* st = (sec == 0) ? stq : stk;
  ushort* out = (sec == 0) ? qp : kp;
  float scale = (sec == 0) ? 0.125f : 1.0f;
  short res[8];
  if (d0 < 32) {
    bf16x8 v = *(const bf16x8*)(zf + ((size_t)(b * S_ + s)) * (H_ * 32) + h * 32 + d0);
#pragma unroll
    for (int j = 0; j < 8; ++j) res[j] = (short)f2bf(b2f((ushort)v[j]) * scale);
  } else {
    const ushort* xr = rf + ((size_t)(b * S_ + s)) * (H_ * 32) + h * 32;
    int dr0 = d0 - 32;
    if (dr0 < 16) {
      bf16x8 xa = *(const bf16x8*)(xr + dr0);
      bf16x8 xb2 = *(const bf16x8*)(xr + dr0 + 16);
#pragma unroll
      for (int j = 0; j < 8; ++j) {
        float c = ct[s * 16 + dr0 + j], sn = st[s * 16 + dr0 + j];
        res[j] = (short)f2bf((b2f((ushort)xa[j]) * c - b2f((ushort)xb2[j]) * sn) * scale);
      }
    } else {
      bf16x8 xa = *(const bf16x8*)(xr + dr0);
      bf16x8 xb2 = *(const bf16x8*)(xr + dr0 - 16);
#pragma unroll
      for (int j = 0; j < 8; ++j) {
        float c = ct[s * 16 + dr0 - 16 + j], sn = st[s * 16 + dr0 - 16 + j];
        res[j] = (short)f2bf((b2f((ushort)xa[j]) * c + b2f((ushort)xb2[j]) * sn) * scale);
      }
    }
  }
  *(bf16x8*)(out + i) = *(bf16x8*)res;
}

// ---------------- MFMA flash attention: QBLK=64, direct-Q, defer-max ----------------
__global__ __launch_bounds__(256) void attn_mfma(const ushort* __restrict__ Q,
    const ushort* __restrict__ K, const ushort* __restrict__ V,
    ushort* __restrict__ O) {
  __shared__ ushort lds[12288];                 // 24 KB: K 8K, Vt 8K, P 8K
  char* kc = (char*)lds;
  char* vc = (char*)lds + 8192;
  char* pc = (char*)lds + 16384;
  int tid = threadIdx.x, lane = tid & 63, wid = tid >> 6;
  int nwg = gridDim.x * gridDim.y;
  int lin = (int)blockIdx.y * gridDim.x + (int)blockIdx.x;
  lin = xcd_swz(lin, nwg);
  int qt = lin % gridDim.x;
  int bh = lin / gridDim.x;
  int q0 = qt << 6;
  int b = bh / H_, h = bh % H_;
  const ushort* Qb = Q + ((size_t)bh * S_ + q0) * HD_;
  const ushort* Kb = K + (size_t)bh * S_ * HD_;
  const ushort* Vb = V + (size_t)bh * S_ * HD_;
  // Q A-fragments straight from global (one-time load; wave-local rows)
  bf16x8 aq[2];
  {
    const ushort* qrow = Qb + (size_t)(wid * 16 + (lane & 15)) * HD_;
#pragma unroll
    for (int kk = 0; kk < 2; ++kk)
      aq[kk] = *(const bf16x8*)(qrow + kk * 32 + ((lane >> 4) << 3));
  }
  f32x4 o_[4];
  float m_[4], l_[4];
#pragma unroll
  for (int i = 0; i < 4; ++i) { o_[i] = (f32x4){0.f,0.f,0.f,0.f}; m_[i] = -1e30f; l_[i] = 0.f; }

  for (int kt = 0; kt < S_ / 64; ++kt) {
    __syncthreads();
    {  // stage K tile (swizzled)
      int r = tid >> 2, c0 = (tid & 3) * 32;
      const char* src = (const char*)(Kb + (size_t)(kt * 64 + r) * HD_);
      uint4 v0 = *(const uint4*)(src + c0);
      uint4 v1 = *(const uint4*)(src + c0 + 16);
      int sw = (r & 7) << 4;
      *(uint4*)(kc + r * 128 + (c0 ^ sw)) = v0;
      *(uint4*)(kc + r * 128 + ((c0 + 16) ^ sw)) = v1;
    }
    {  // stage V tile transposed (paired-key b32 writes)
      int kp = tid & 31, g = tid >> 5, d0 = g * 8;
      const ushort* s0 = Vb + (size_t)(kt * 64 + 2 * kp) * HD_ + d0;
      bf16x8 va = *(const bf16x8*)s0;
      bf16x8 vb2 = *(const bf16x8*)(s0 + HD_);
#pragma unroll
      for (int j = 0; j < 8; ++j) {
        int d = d0 + j;
        uint val = (uint)(ushort)va[j] | ((uint)(ushort)vb2[j] << 16);
        *(uint*)(vc + d * 128 + ((kp * 4) ^ ((d & 7) << 4))) = val;
      }
    }
    __syncthreads();
    f32x4 sacc[4];
    __builtin_amdgcn_s_setprio(1);
#pragma unroll
    for (int ksub = 0; ksub < 4; ++ksub) {
      sacc[ksub] = (f32x4){0.f,0.f,0.f,0.f};
#pragma unroll
      for (int kk = 0; kk < 2; ++kk) {
        int r = ksub * 16 + (lane & 15);
        int c2 = kk * 64 + ((lane >> 4) << 4);
        bf16x8 bk = *(bf16x8*)(kc + r * 128 + (c2 ^ ((r & 7) << 4)));
        sacc[ksub] = __builtin_amdgcn_mfma_f32_16x16x32_bf16(aq[kk], bk, sacc[ksub], 0, 0, 0);
      }
    }
    __builtin_amdgcn_s_setprio(0);
    float p[4][4];
#pragma unroll
    for (int rr = 0; rr < 4; ++rr) {
      float cm = fmaxf(fmaxf(sacc[0][rr], sacc[1][rr]), fmaxf(sacc[2][rr], sacc[3][rr]));
      cm = fmaxf(cm, __shfl_xor(cm, 1));
      cm = fmaxf(cm, __shfl_xor(cm, 2));
      cm = fmaxf(cm, __shfl_xor(cm, 4));
      cm = fmaxf(cm, __shfl_xor(cm, 8));
      // T13 defer-max: skip rescale when per-tile max growth <= 8 (wave-uniform)
      bool keep = __all(cm - m_[rr] <= 8.0f);
      float mn = keep ? m_[rr] : fmaxf(m_[rr], cm);
      float ps = 0.f;
#pragma unroll
      for (int ksub = 0; ksub < 4; ++ksub) {
        float pv = __expf(sacc[ksub][rr] - mn);
        p[ksub][rr] = pv;
        ps += pv;
      }
      ps += __shfl_xor(ps, 1);
      ps += __shfl_xor(ps, 2);
      ps += __shfl_xor(ps, 4);
      ps += __shfl_xor(ps, 8);
      if (keep) {
        l_[rr] += ps;
      } else {
        float al = __expf(m_[rr] - mn);
        l_[rr] = l_[rr] * al + ps;
        m_[rr] = mn;
#pragma unroll
        for (int ds = 0; ds < 4; ++ds) o_[ds][rr] *= al;
      }
    }
#pragma unroll
    for (int ksub = 0; ksub < 4; ++ksub)
#pragma unroll
      for (int rr = 0; rr < 4; ++rr) {
        int r = wid * 16 + ((lane >> 4) << 2) + rr;
        int cb = (ksub * 16 + (lane & 15)) * 2;
        *(ushort*)(pc + r * 128 + (cb ^ ((r & 7) << 4))) = f2bf(p[ksub][rr]);
      }
    __builtin_amdgcn_s_setprio(1);
#pragma unroll
    for (int kk2 = 0; kk2 < 2; ++kk2) {
      int rA = wid * 16 + (lane & 15);
      int c2 = kk2 * 64 + ((lane >> 4) << 4);
      bf16x8 ap = *(bf16x8*)(pc + rA * 128 + (c2 ^ ((rA & 7) << 4)));
#pragma unroll
      for (int ds = 0; ds < 4; ++ds) {
        int rB = ds * 16 + (lane & 15);
        bf16x8 bv = *(bf16x8*)(vc + rB * 128 + (c2 ^ ((rB & 7) << 4)));
        o_[ds] = __builtin_amdgcn_mfma_f32_16x16x32_bf16(ap, bv, o_[ds], 0, 0, 0);
      }
    }
    __builtin_amdgcn_s_setprio(0);
  }
#pragma unroll
  for (int rr = 0; rr < 4; ++rr) {
    float inv = 1.f / l_[rr];
    int q = q0 + wid * 16 + ((lane >> 4) << 2) + rr;
#pragma unroll
    for (int ds = 0; ds < 4; ++ds) {
      int d = ds * 16 + (lane & 15);
      O[((size_t)(b * S_ + q)) * D3_ + h * HD_ + d] = f2bf(o_[ds][rr] * inv);
    }
  }
}

// ---------------- host ----------------
extern "C" void kernel_launch(void* const* d_in, const int* in_sizes, int n_in,
                              void* d_out, int out_size, void* d_ws, size_t ws_size,
                              hipStream_t stream) {
  const float* input_q = (const float*)d_in[0];
  const float* ln_q_w  = (const float*)d_in[1];
  const float* ln_kv_w = (const float*)d_in[2];
  const float* dirty_zq  = (const float*)d_in[15];
  const float* dirty_zkv = (const float*)d_in[16];
  const float* e2de    = (const float*)d_in[17];
  const float* rope_q_f = (const float*)d_in[31];
  const float* rope_k_f = (const float*)d_in[32];
  const float* ln2_w   = (const float*)d_in[34];
  const float* eps_zq  = (const float*)d_in[37];
  const float* eps_zkv = (const float*)d_in[38];

  ushort* wsu = (ushort*)d_ws;
  ushort* wb    = wsu;                        // weights bf16 [0, 12124160)
  ushort* xq_b  = wsu + 12124160;             // [8,1024,768] bf16
  ushort* xkv_b = wsu + 18415616;
  ushort* xqT   = wsu + 37289984;             // [8,768,1024]
  ushort* xkvT  = wsu + 43581440;
  ushort* inT   = wsu + 49872896;
  ushort* t1q   = wsu + 12124160;             // (xq_b/xkv_b dead after transposes)
  ushort* t1kv  = wsu + 15269888;
  ushort* t2b   = wsu + 24707072;             // [32][256][512] -> ends 28901376
  ushort* mv    = wsu + 28901376;             // [32][256][256] -> ends 30998528
  ushort* zqb   = wsu + 30998528;
  ushort* zkvb  = wsu + 31522816;
  ushort* zqT   = wsu + 32047104;
  ushort* zkvT  = wsu + 32571392;             // ends 33095680
  ushort* up    = wsu + 12124160;             // [4][8][1024][256] (t1 dead) -> ends 20512768
  ushort* vzf   = wsu + 20512768;             // [8192,768] -> ends 26804224 (t2b dead)
  ushort* mid   = wsu + 56164352;             // [3][8192][512] -> ends 68747264
  ushort* tkr   = wsu + 37289984;             // (xqT dead)
  ushort* qzf   = wsu + 68747264;
  ushort* kzf   = wsu + 71892992;
  ushort* qrf   = wsu + 75038720;
  ushort* krf   = wsu + 78184448;
  float*  ctq   = (float*)(wsu + 81330176);
  float*  stq   = ctq + 16384;
  float*  ctk   = ctq + 32768;
  float*  stk   = ctq + 49152;
  ushort* qp    = wsu + 12124160;             // (up dead after step 11)
  ushort* kp    = wsu + 43581440;             // (xkvT dead)
  ushort* vp    = wsu + 49872896;             // (inT dead after step 14)
  ushort* ofb   = wsu + 56164352;             // (mid dead)
  float*  xb    = (float*)(wsu + 12124160);   // (qp/vzf dead after attn/packs)
  ushort* ylb   = wsu + 37289984;             // (tkr dead)
  ushort* hm    = wsu + 43581440;             // [8192,3072] (kp/vp/ofb dead)

  const int W_mq = 0,       W_mkv = 524288;
  const int Wq1 = 1048576,  Wv1 = 1441792,  Wk1 = 1835008,  Wkv1 = 2228224;
  const int Wq2 = 2621440,  Wv2 = 2752512,  Wk2 = 2883584,  Wkv2 = 3014656;
  const int W_qzu = 3145728, W_kzu = 3407872, W_vzu = 3670016, W_qr = 3932160;
  const int W_kr = 4194304, W_qzup = 5242880, W_kzup = 5373952, W_vzup = 5505024;
  const int W_qw = 5636096, W_kw = 5832704,  W_vw = 6029312,  W_qrw = 6422528;
  const int W_krw = 6520832, W_ow = 6815744, W_m1 = 7405568,  W_m2 = 9764864;

  // 1) dual LN -> bf16
  ln_dual_b<<<B_ * S_, 256, 0, stream>>>(input_q, ln_q_w, ln_kv_w, xq_b, xkv_b, D1_);

  // 2) transposes to [b, D, S]
  {
    dim3 g(D1_ / 32, S_ / 32, B_);
    trans_b2b<<<g, 256, 0, stream>>>(xq_b, xqT, S_, D1_, (long)S_ * D1_);
    trans_b2b<<<g, 256, 0, stream>>>(xkv_b, xkvT, S_, D1_, (long)S_ * D1_);
    trans_f2b<<<g, 256, 0, stream>>>(input_q, inT, S_, D1_, (long)S_ * D1_);
  }

  // 3) weights -> bf16 + RoPE tables
  {
    ConvTab t;
    const int srcIdx[28] = {3,4,5,6, 7,9,11,13, 8,10,12,14, 18,19,20,21, 22,
                            23,24,25, 26,27, 28, 29, 30, 33, 35, 36};
    const int sz[28] = {262144,262144,262144,262144, 393216,393216,393216,393216,
                        131072,131072,131072,131072, 262144,262144,262144,262144,
                        1048576, 131072,131072,131072, 196608,196608, 393216,
                        98304, 294912, 589824, 2359296, 2359296};
    int off = 0, c4 = 0;
    for (int i = 0; i < 28; ++i) {
      t.src[i] = (const float*)d_in[srcIdx[i]];
      t.off[i] = off;
      t.cum[i] = c4;
      off += sz[i];
      c4 += sz[i] / 4;
    }
    t.cum[28] = c4;
    multi_f2b<<<(c4 + 255) / 256, 256, 0, stream>>>(t, wb, c4);
    rope_tab<<<64, 256, 0, stream>>>(rope_q_f, rope_k_f, ctq, stq, ctk, stk, 16384);
  }

  long sXT = (long)S_ * D1_;

  // 4) grouped seq-compress: z=16
  {
    GrpTab t;
    for (int c = 0; c < 2; ++c)
      for (int b = 0; b < 8; ++b) {
        int z = c * 8 + b;
        t.A[z] = wb + (c == 0 ? W_mq : W_mkv);
        t.Bm[z] = (c == 0 ? xqT : xkvT) + (size_t)b * sXT;
        t.C[z] = (c == 0 ? t1q : t1kv) + (size_t)b * 512 * 768;
      }
    dim3 g(D1_ / 128, 512 / 128, 16);
    gemm_grp<<<g, 256, 0, stream>>>(t, 512, D1_, S_);
  }
  // 5) grouped w1: z=32
  {
    GrpTab t;
    const int wo[4] = {Wq1, Wv1, Wk1, Wkv1};
    for (int c = 0; c < 4; ++c)
      for (int b = 0; b < 8; ++b) {
        int z = c * 8 + b;
        ushort* t1 = (c < 2 ? t1q : t1kv);
        t.A[z] = t1 + (size_t)b * 512 * 768 + (size_t)(c & 1) * 256 * 768;
        t.Bm[z] = wb + wo[c];
        t.C[z] = t2b + (size_t)z * 256 * 512;
      }
    dim3 g(D2_ / 128, 256 / 128, 32);
    gemm_grp<<<g, 256, 0, stream>>>(t, 256, D2_, D1_);
  }
  // 6) grouped w2: z=32
  {
    GrpTab t;
    const int wo[4] = {Wq2, Wv2, Wk2, Wkv2};
    for (int c = 0; c < 4; ++c)
      for (int b = 0; b < 8; ++b) {
        int z = c * 8 + b;
        t.A[z] = t2b + (size_t)z * 256 * 512;
        t.Bm[z] = wb + wo[c];
        t.C[z] = mv + (size_t)z * 256 * 256;
      }
    dim3 g(MVH_ / 128, 256 / 128, 32);
    gemm_grp<<<g, 256, 0, stream>>>(t, 256, MVH_, D2_);
  }
  // 7) reparam
  z_combine_b<<<(B_ * SR_ * MVH_) / 256, 256, 0, stream>>>(mv, mv + 8 * 65536,
      eps_zq, dirty_zq, e2de, zqb, B_ * SR_ * MVH_, SR_ * MVH_);
  z_combine_b<<<(B_ * SR_ * MVH_) / 256, 256, 0, stream>>>(mv + 16 * 65536,
      mv + 24 * 65536, eps_zkv, dirty_zkv, e2de, zkvb, B_ * SR_ * MVH_, SR_ * MVH_);
  // 8) z transposes
  {
    dim3 g(MVH_ / 32, SR_ / 32, B_);
    trans_b2b<<<g, 256, 0, stream>>>(zqb, zqT, SR_, MVH_, (long)SR_ * MVH_);
    trans_b2b<<<g, 256, 0, stream>>>(zkvb, zkvT, SR_, MVH_, (long)SR_ * MVH_);
  }
  // 9) grouped upsample-1: z=32
  {
    GrpTab t;
    const int wo[4] = {W_qzu, W_kzu, W_vzu, W_qr};
    for (int c = 0; c < 4; ++c)
      for (int b = 0; b < 8; ++b) {
        int z = c * 8 + b;
        t.A[z] = wb + wo[c];
        t.Bm[z] = ((c == 0 || c == 3) ? zqT : zkvT) + (size_t)b * 65536;
        t.C[z] = up + (size_t)z * 1024 * 256;
      }
    dim3 g(MVH_ / 128, SN_ / 128, 32);
    gemm_grp<<<g, 256, 0, stream>>>(t, SN_, MVH_, SR_);
  }
  // 10) grouped upsample-2 (qz,kz,vz): z=3
  {
    GrpTab t;
    const int wo[3] = {W_qzup, W_kzup, W_vzup};
    for (int c = 0; c < 3; ++c) {
      t.A[c] = up + (size_t)c * 8 * 1024 * 256;
      t.Bm[c] = wb + wo[c];
      t.C[c] = mid + (size_t)c * 8192 * 512;
    }
    dim3 g(D2_ / 128, (B_ * SN_) / 128, 3);
    gemm_grp<<<g, 256, 0, stream>>>(t, B_ * SN_, D2_, MVH_);
  }
  // 11) qr stage-2
  {
    dim3 g(384 / 128, (B_ * SN_) / 128, 1);
    gemm_bf16<0><<<g, 256, 0, stream>>>(up + (size_t)3 * 8 * 1024 * 256, 0,
        wb + W_qrw, 0, nullptr, qrf, 0, B_ * SN_, 384, MVH_);
  }
  // 12) grouped stage-3 (q_w, k_w): z=2
  {
    GrpTab t;
    t.A[0] = mid;                      t.Bm[0] = wb + W_qw; t.C[0] = qzf;
    t.A[1] = mid + (size_t)8192 * 512; t.Bm[1] = wb + W_kw; t.C[1] = kzf;
    dim3 g(384 / 128, (B_ * SN_) / 128, 2);
    gemm_grp<<<g, 256, 0, stream>>>(t, B_ * SN_, 384, D2_);
  }
  // 13) v_w
  {
    dim3 g(D3_ / 128, (B_ * SN_) / 128, 1);
    gemm_bf16<0><<<g, 256, 0, stream>>>(mid + (size_t)2 * 8192 * 512, 0,
        wb + W_vw, 0, nullptr, vzf, 0, B_ * SN_, D3_, D2_);
  }
  // 14) kr stage-1 (strided batch)
  {
    dim3 g(D1_ / 128, SN_ / 128, B_);
    gemm_bf16<0><<<g, 256, 0, stream>>>(wb + W_kr, 0, inT, sXT, nullptr, tkr,
        (long)SN_ * D1_, SN_, D1_, S_);
  }
  // 15) kr stage-2
  {
    dim3 g(384 / 128, (B_ * SN_) / 128, 1);
    gemm_bf16<0><<<g, 256, 0, stream>>>(tkr, 0, wb + W_krw, 0, nullptr, krf, 0,
        B_ * SN_, 384, D1_);
  }

  // 16) fused pack (q, k, v sections)
  int nblk = (B_ * H_ * S_ * HD_) / 8 / 256;   // 3072 blocks per section
  pack_all<<<3 * nblk, 256, 0, stream>>>(qzf, qrf, ctq, stq, qp,
                                         kzf, krf, ctk, stk, kp, vzf, vp, nblk);

  // 17) attention (QBLK=64, direct-Q, defer-max)
  {
    dim3 g(S_ / 64, B_ * H_);
    attn_mfma<<<g, 256, 0, stream>>>(qp, kp, vp, ofb);
  }

  // 18) epilogue
  {
    dim3 g(D3_ / 128, (B_ * SN_) / 128);
    gemm_bf16<1><<<g, 256, 0, stream>>>(ofb, 0, wb + W_ow, 0, input_q, xb, 0,
                                        B_ * SN_, D3_, D3_);
  }
  ln_b<<<B_ * SN_, 256, 0, stream>>>(xb, ln2_w, ylb, D3_);
  {
    dim3 g(MLP_ / 128, (B_ * SN_) / 128);
    gemm_bf16<2><<<g, 256, 0, stream>>>(ylb, 0, wb + W_m1, 0, nullptr, hm, 0,
                                        B_ * SN_, MLP_, D3_);
  }
  {
    dim3 g(D3_ / 128, (B_ * SN_) / 128);
    gemm_bf16<1><<<g, 256, 0, stream>>>(hm, 0, wb + W_m2, 0, xb, (float*)d_out, 0,
                                        B_ * SN_, D3_, MLP_);
  }
}

// Round 19
// 491.610 us; speedup vs baseline: 1.1239x; 1.1239x over previous
//
#include <hip/hip_runtime.h>
#include <math.h>

#define B_   8
#define S_   1024
#define SR_  256
#define SN_  1024
#define D1_  768
#define D2_  512
#define D3_  768
#define MVH_ 256
#define H_   12
#define HD_  64
#define MLP_ 3072

typedef __attribute__((ext_vector_type(8))) short bf16x8;
typedef __attribute__((ext_vector_type(4))) float f32x4;

__device__ inline ushort f2bf(float f) {
  uint u = __float_as_uint(f);
  uint r = (u + 0x7fffu + ((u >> 16) & 1u)) >> 16;
  return (ushort)r;
}
__device__ inline float b2f(ushort u) { return __uint_as_float(((uint)u) << 16); }

__device__ inline void gload16(const void* g, void* l) {
  __builtin_amdgcn_global_load_lds(
      (const __attribute__((address_space(1))) void*)g,
      (__attribute__((address_space(3))) void*)l, 16, 0, 0);
}

// bijective XCD-aware work remap (m204)
__device__ inline int xcd_swz(int lin, int n) {
  int xcd = lin & 7, idx = lin >> 3;
  int q = n >> 3, r = n & 7;
  return (xcd < r ? xcd * (q + 1) : r * (q + 1) + (xcd - r) * q) + idx;
}

// ---------------- LayerNorm (dual bf16 out) ----------------
__global__ __launch_bounds__(256) void ln_dual_b(const float* __restrict__ x,
    const float* __restrict__ w1, const float* __restrict__ w2,
    ushort* __restrict__ o1, ushort* __restrict__ o2, int D) {
  int row = blockIdx.x;
  const float* xr = x + (size_t)row * D;
  int tid = threadIdx.x;
  float s = 0.f, ss = 0.f;
  for (int i = tid; i < D; i += 256) { float v = xr[i]; s += v; ss += v * v; }
  __shared__ float rs[256];
  __shared__ float rq[256];
  rs[tid] = s; rq[tid] = ss;
  __syncthreads();
  for (int off = 128; off > 0; off >>= 1) {
    if (tid < off) { rs[tid] += rs[tid + off]; rq[tid] += rq[tid + off]; }
    __syncthreads();
  }
  float mu  = rs[0] / (float)D;
  float var = rq[0] / (float)D - mu * mu;
  float inv = rsqrtf(var + 1e-6f);
  for (int i = tid; i < D; i += 256) {
    float v = (xr[i] - mu) * inv;
    o1[(size_t)row * D + i] = f2bf(v * w1[i]);
    o2[(size_t)row * D + i] = f2bf(v * w2[i]);
  }
}

// ---------------- LayerNorm (bf16 out, single) ----------------
__global__ __launch_bounds__(256) void ln_b(const float* __restrict__ x,
    const float* __restrict__ w, ushort* __restrict__ o, int D) {
  int row = blockIdx.x;
  const float* xr = x + (size_t)row * D;
  int tid = threadIdx.x;
  float s = 0.f, ss = 0.f;
  for (int i = tid; i < D; i += 256) { float v = xr[i]; s += v; ss += v * v; }
  __shared__ float rs[256];
  __shared__ float rq[256];
  rs[tid] = s; rq[tid] = ss;
  __syncthreads();
  for (int off = 128; off > 0; off >>= 1) {
    if (tid < off) { rs[tid] += rs[tid + off]; rq[tid] += rq[tid + off]; }
    __syncthreads();
  }
  float mu  = rs[0] / (float)D;
  float var = rq[0] / (float)D - mu * mu;
  float inv = rsqrtf(var + 1e-6f);
  for (int i = tid; i < D; i += 256) {
    float v = (xr[i] - mu) * inv;
    o[(size_t)row * D + i] = f2bf(v * w[i]);
  }
}

// ---------------- transpose fp32 -> bf16 ----------------
__global__ __launch_bounds__(256) void trans_f2b(const float* __restrict__ in,
    ushort* __restrict__ out, int R, int C, long strideEl) {
  __shared__ float tile[32][33];
  int bb = blockIdx.z;
  const float* ib = in + (size_t)bb * strideEl;
  ushort* ob = out + (size_t)bb * strideEl;
  int c0 = blockIdx.x << 5, r0 = blockIdx.y << 5;
  int tx = threadIdx.x & 31, ty = threadIdx.x >> 5;
#pragma unroll
  for (int i = 0; i < 4; ++i)
    tile[ty + 8 * i][tx] = ib[(size_t)(r0 + ty + 8 * i) * C + c0 + tx];
  __syncthreads();
#pragma unroll
  for (int i = 0; i < 4; ++i)
    ob[(size_t)(c0 + ty + 8 * i) * R + r0 + tx] = f2bf(tile[tx][ty + 8 * i]);
}

// ---------------- transpose bf16 -> bf16 ----------------
__global__ __launch_bounds__(256) void trans_b2b(const ushort* __restrict__ in,
    ushort* __restrict__ out, int R, int C, long strideEl) {
  __shared__ ushort tile[32][33];
  int bb = blockIdx.z;
  const ushort* ib = in + (size_t)bb * strideEl;
  ushort* ob = out + (size_t)bb * strideEl;
  int c0 = blockIdx.x << 5, r0 = blockIdx.y << 5;
  int tx = threadIdx.x & 31, ty = threadIdx.x >> 5;
#pragma unroll
  for (int i = 0; i < 4; ++i)
    tile[ty + 8 * i][tx] = ib[(size_t)(r0 + ty + 8 * i) * C + c0 + tx];
  __syncthreads();
#pragma unroll
  for (int i = 0; i < 4; ++i)
    ob[(size_t)(c0 + ty + 8 * i) * R + r0 + tx] = tile[tx][ty + 8 * i];
}

// ---------------- multi-tensor fp32 -> bf16 weight conversion ----------------
struct ConvTab {
  const float* src[28];
  int off[28];
  int cum[29];
};
__global__ __launch_bounds__(256) void multi_f2b(ConvTab t, ushort* __restrict__ wb,
                                                 int total4) {
  int i = blockIdx.x * 256 + threadIdx.x;
  if (i >= total4) return;
  int ti = 0;
  while (t.cum[ti + 1] <= i) ++ti;
  int j = i - t.cum[ti];
  float4 v = ((const float4*)t.src[ti])[j];
  ushort4 o;
  o.x = f2bf(v.x); o.y = f2bf(v.y); o.z = f2bf(v.z); o.w = f2bf(v.w);
  ((ushort4*)(wb + t.off[ti]))[j] = o;
}

// ---------------- RoPE cos/sin tables ----------------
__global__ __launch_bounds__(256) void rope_tab(const float* __restrict__ fq,
    const float* __restrict__ fk, float* __restrict__ ctq, float* __restrict__ stq,
    float* __restrict__ ctk, float* __restrict__ stk, int n) {
  int i = blockIdx.x * 256 + threadIdx.x;
  if (i >= n) return;
  float a = fq[i]; ctq[i] = cosf(a); stq[i] = sinf(a);
  float c = fk[i]; ctk[i] = cosf(c); stk[i] = sinf(c);
}

// ---- shared BK=64 GEMM core body ----
#define GEMM_BODY(Ab, Bb, STORE)                                                     \
  __shared__ ushort As[128 * 64];                                                    \
  __shared__ ushort Bs[128 * 64];                                                    \
  int tid = threadIdx.x;                                                             \
  int lane = tid & 63, wid = tid >> 6;                                               \
  int m0 = by << 7, n0 = bx << 7;                                                    \
  int wm = (wid >> 1) << 6, wn = (wid & 1) << 6;                                     \
  f32x4 acc[4][4];                                                                   \
  _Pragma("unroll")                                                                  \
  for (int i = 0; i < 4; ++i)                                                        \
    _Pragma("unroll")                                                                \
    for (int j = 0; j < 4; ++j) acc[i][j] = (f32x4){0.f, 0.f, 0.f, 0.f};             \
  char* asb = (char*)As;                                                             \
  char* bsb = (char*)Bs;                                                             \
  int srow = lane >> 3;                                                              \
  int skb  = (lane & 7) << 4;                                                        \
  for (int k0 = 0; k0 < K; k0 += 64) {                                               \
    __syncthreads();                                                                 \
    _Pragma("unroll")                                                                \
    for (int i = 0; i < 4; ++i) {                                                    \
      int rr = wid * 32 + i * 8;                                                     \
      gload16((const char*)Ab + ((size_t)(m0 + rr + srow) * K + k0) * 2 + skb,       \
              asb + rr * 128);                                                       \
      gload16((const char*)Bb + ((size_t)(n0 + rr + srow) * K + k0) * 2 + skb,       \
              bsb + rr * 128);                                                       \
    }                                                                                \
    __syncthreads();                                                                 \
    bf16x8 af[2][4], bf[2][4];                                                       \
    _Pragma("unroll")                                                                \
    for (int h = 0; h < 2; ++h) {                                                    \
      _Pragma("unroll")                                                              \
      for (int m = 0; m < 4; ++m)                                                    \
        af[h][m] = *(bf16x8*)&As[(wm + m * 16 + (lane & 15)) * 64 + h * 32 +         \
                                 ((lane >> 4) << 3)];                                \
      _Pragma("unroll")                                                              \
      for (int n = 0; n < 4; ++n)                                                    \
        bf[h][n] = *(bf16x8*)&Bs[(wn + n * 16 + (lane & 15)) * 64 + h * 32 +         \
                                 ((lane >> 4) << 3)];                                \
    }                                                                                \
    __builtin_amdgcn_s_setprio(1);                                                   \
    _Pragma("unroll")                                                                \
    for (int h = 0; h < 2; ++h)                                                      \
      _Pragma("unroll")                                                              \
      for (int m = 0; m < 4; ++m)                                                    \
        _Pragma("unroll")                                                            \
        for (int n = 0; n < 4; ++n)                                                  \
          acc[m][n] = __builtin_amdgcn_mfma_f32_16x16x32_bf16(af[h][m], bf[h][n],    \
                                                              acc[m][n], 0, 0, 0);   \
    __builtin_amdgcn_s_setprio(0);                                                   \
  }                                                                                  \
  int cr = (lane >> 4) << 2, cc = lane & 15;                                         \
  _Pragma("unroll")                                                                  \
  for (int m = 0; m < 4; ++m)                                                        \
    _Pragma("unroll")                                                                \
    for (int n = 0; n < 4; ++n) {                                                    \
      _Pragma("unroll")                                                              \
      for (int r = 0; r < 4; ++r) {                                                  \
        int row = m0 + wm + m * 16 + cr + r;                                         \
        int col = n0 + wn + n * 16 + cc;                                             \
        float v = acc[m][n][r];                                                      \
        STORE;                                                                       \
      }                                                                              \
    }

// ---------------- bf16 MFMA GEMM (strided batch): C_b = A_b @ B_b^T ----------------
template <int EPI>
__global__ __launch_bounds__(256) void gemm_bf16(const ushort* __restrict__ A, long sA,
    const ushort* __restrict__ Bm, long sB, const float* __restrict__ R,
    void* __restrict__ Cout, long sC, int M, int N, int K) {
  int gx = gridDim.x, gy = gridDim.y;
  int nwg = gx * gy * gridDim.z;
  int lin = ((int)blockIdx.z * gy + (int)blockIdx.y) * gx + (int)blockIdx.x;
  lin = xcd_swz(lin, nwg);
  int bx = lin % gx, tt = lin / gx;
  int by = tt % gy, bb = tt / gy;
  const ushort* Ab = A + (size_t)bb * sA;
  const ushort* Bb = Bm + (size_t)bb * sB;
  GEMM_BODY(Ab, Bb,
    if (EPI == 0) {
      ((ushort*)Cout)[(size_t)bb * sC + (size_t)row * N + col] = f2bf(v);
    } else if (EPI == 1) {
      ((float*)Cout)[(size_t)row * N + col] = v + R[(size_t)row * N + col];
    } else {
      float y = 0.7978845608f * (v + 0.044715f * v * v * v);
      float sg = 1.0f / (1.0f + __expf(-2.0f * y));
      ((ushort*)Cout)[(size_t)row * N + col] = f2bf(v * sg);
    })
}

// ---------------- grouped bf16 MFMA GEMM ----------------
struct GrpTab {
  const ushort* A[32];
  const ushort* Bm[32];
  ushort* C[32];
};
__global__ __launch_bounds__(256) void gemm_grp(GrpTab t, int M, int N, int K) {
  int gx = gridDim.x, gy = gridDim.y;
  int nwg = gx * gy * gridDim.z;
  int lin = ((int)blockIdx.z * gy + (int)blockIdx.y) * gx + (int)blockIdx.x;
  lin = xcd_swz(lin, nwg);
  int bx = lin % gx, tt = lin / gx;
  int by = tt % gy, zz = tt / gy;
  const ushort* Ab = t.A[zz];
  const ushort* Bb = t.Bm[zz];
  ushort* Cb = t.C[zz];
  GEMM_BODY(Ab, Bb, Cb[(size_t)row * N + col] = f2bf(v))
}

// ---------------- reparameterization (bf16 in/out) ----------------
__global__ __launch_bounds__(256) void z_combine_b(const ushort* __restrict__ mean,
    const ushort* __restrict__ var, const float* __restrict__ eps,
    const float* __restrict__ dirty, const float* __restrict__ e2de_p,
    ushort* __restrict__ zout, int total, int perBatch) {
  int i = blockIdx.x * 256 + threadIdx.x;
  if (i >= total) return;
  float e = e2de_p[0];
  float v = b2f(mean[i]) +
            (e * eps[i] + (1.0f - e) * dirty[i % perBatch]) * expf(0.5f * b2f(var[i]));
  zout[i] = f2bf(v);
}

// ---------------- fused head pack + RoPE (q / k / v sections) ----------------
__global__ __launch_bounds__(256) void pack_all(
    const ushort* __restrict__ qzf, const ushort* __restrict__ qrf,
    const float* __restrict__ ctq, const float* __restrict__ stq, ushort* __restrict__ qp,
    const ushort* __restrict__ kzf, const ushort* __restrict__ krf,
    const float* __restrict__ ctk, const float* __restrict__ stk, ushort* __restrict__ kp,
    const ushort* __restrict__ vzf, ushort* __restrict__ vp, int nblk) {
  int sec = blockIdx.x / nblk;
  int blk = blockIdx.x - sec * nblk;
  int i8 = blk * 256 + threadIdx.x;
  int i = i8 << 3;
  int d0 = i & 63;
  int s = (i >> 6) & (S_ - 1);
  int bh = i >> 16;
  int b = bh / H_, h = bh % H_;
  if (sec == 2) {
    bf16x8 v = *(const bf16x8*)(vzf + ((size_t)(b * S_ + s)) * D3_ + h * 64 + d0);
    *(bf16x8*)(vp + i) = v;
    return;
  }
  const ushort* zf = (sec == 0) ? qzf : kzf;
  const ushort* rf = (sec == 0) ? qrf : krf;
  const float* ct = (sec == 0) ? ctq : ctk;
  const float* st = (sec == 0) ? stq : stk;
  ushort* out = (sec == 0) ? qp : kp;
  float scale = (sec == 0) ? 0.125f : 1.0f;
  short res[8];
  if (d0 < 32) {
    bf16x8 v = *(const bf16x8*)(zf + ((size_t)(b * S_ + s)) * (H_ * 32) + h * 32 + d0);
#pragma unroll
    for (int j = 0; j < 8; ++j) res[j] = (short)f2bf(b2f((ushort)v[j]) * scale);
  } else {
    const ushort* xr = rf + ((size_t)(b * S_ + s)) * (H_ * 32) + h * 32;
    int dr0 = d0 - 32;
    if (dr0 < 16) {
      bf16x8 xa = *(const bf16x8*)(xr + dr0);
      bf16x8 xb2 = *(const bf16x8*)(xr + dr0 + 16);
#pragma unroll
      for (int j = 0; j < 8; ++j) {
        float c = ct[s * 16 + dr0 + j], sn = st[s * 16 + dr0 + j];
        res[j] = (short)f2bf((b2f((ushort)xa[j]) * c - b2f((ushort)xb2[j]) * sn) * scale);
      }
    } else {
      bf16x8 xa = *(const bf16x8*)(xr + dr0);
      bf16x8 xb2 = *(const bf16x8*)(xr + dr0 - 16);
#pragma unroll
      for (int j = 0; j < 8; ++j) {
        float c = ct[s * 16 + dr0 - 16 + j], sn = st[s * 16 + dr0 - 16 + j];
        res[j] = (short)f2bf((b2f((ushort)xa[j]) * c + b2f((ushort)xb2[j]) * sn) * scale);
      }
    }
  }
  *(bf16x8*)(out + i) = *(bf16x8*)res;
}

// ---------------- MFMA flash attention: QBLK=64 + setprio (round-14 verified) ----------------
__global__ __launch_bounds__(256) void attn_mfma(const ushort* __restrict__ Q,
    const ushort* __restrict__ K, const ushort* __restrict__ V,
    ushort* __restrict__ O) {
  __shared__ ushort lds[16384];                 // 32 KB
  char* qc = (char*)lds;
  char* kc = (char*)lds + 8192;
  char* vc = (char*)lds + 16384;
  char* pc = (char*)lds + 24576;
  int tid = threadIdx.x, lane = tid & 63, wid = tid >> 6;
  int nwg = gridDim.x * gridDim.y;
  int lin = (int)blockIdx.y * gridDim.x + (int)blockIdx.x;
  lin = xcd_swz(lin, nwg);
  int qt = lin % gridDim.x;
  int bh = lin / gridDim.x;
  int q0 = qt << 6;
  int b = bh / H_, h = bh % H_;
  const ushort* Qb = Q + ((size_t)bh * S_ + q0) * HD_;
  const ushort* Kb = K + (size_t)bh * S_ * HD_;
  const ushort* Vb = V + (size_t)bh * S_ * HD_;
  {
    int r = tid >> 2, c0 = (tid & 3) * 32;
    const char* src = (const char*)Qb + r * 128;
    uint4 v0 = *(const uint4*)(src + c0);
    uint4 v1 = *(const uint4*)(src + c0 + 16);
    int sw = (r & 7) << 4;
    *(uint4*)(qc + r * 128 + (c0 ^ sw)) = v0;
    *(uint4*)(qc + r * 128 + ((c0 + 16) ^ sw)) = v1;
  }
  __syncthreads();
  bf16x8 aq[2];
  {
    int r = wid * 16 + (lane & 15);
    int sw = (r & 7) << 4;
#pragma unroll
    for (int kk = 0; kk < 2; ++kk) {
      int c2 = kk * 64 + ((lane >> 4) << 4);
      aq[kk] = *(bf16x8*)(qc + r * 128 + (c2 ^ sw));
    }
  }
  f32x4 o_[4];
  float m_[4], l_[4];
#pragma unroll
  for (int i = 0; i < 4; ++i) { o_[i] = (f32x4){0.f,0.f,0.f,0.f}; m_[i] = -1e30f; l_[i] = 0.f; }

  for (int kt = 0; kt < S_ / 64; ++kt) {
    __syncthreads();
    {
      int r = tid >> 2, c0 = (tid & 3) * 32;
      const char* src = (const char*)(Kb + (size_t)(kt * 64 + r) * HD_);
      uint4 v0 = *(const uint4*)(src + c0);
      uint4 v1 = *(const uint4*)(src + c0 + 16);
      int sw = (r & 7) << 4;
      *(uint4*)(kc + r * 128 + (c0 ^ sw)) = v0;
      *(uint4*)(kc + r * 128 + ((c0 + 16) ^ sw)) = v1;
    }
    {
      int kp = tid & 31, g = tid >> 5, d0 = g * 8;
      const ushort* s0 = Vb + (size_t)(kt * 64 + 2 * kp) * HD_ + d0;
      bf16x8 va = *(const bf16x8*)s0;
      bf16x8 vb2 = *(const bf16x8*)(s0 + HD_);
#pragma unroll
      for (int j = 0; j < 8; ++j) {
        int d = d0 + j;
        uint val = (uint)(ushort)va[j] | ((uint)(ushort)vb2[j] << 16);
        *(uint*)(vc + d * 128 + ((kp * 4) ^ ((d & 7) << 4))) = val;
      }
    }
    __syncthreads();
    f32x4 sacc[4];
    __builtin_amdgcn_s_setprio(1);
#pragma unroll
    for (int ksub = 0; ksub < 4; ++ksub) {
      sacc[ksub] = (f32x4){0.f,0.f,0.f,0.f};
#pragma unroll
      for (int kk = 0; kk < 2; ++kk) {
        int r = ksub * 16 + (lane & 15);
        int c2 = kk * 64 + ((lane >> 4) << 4);
        bf16x8 bk = *(bf16x8*)(kc + r * 128 + (c2 ^ ((r & 7) << 4)));
        sacc[ksub] = __builtin_amdgcn_mfma_f32_16x16x32_bf16(aq[kk], bk, sacc[ksub], 0, 0, 0);
      }
    }
    __builtin_amdgcn_s_setprio(0);
    float p[4][4];
#pragma unroll
    for (int rr = 0; rr < 4; ++rr) {
      float cm = fmaxf(fmaxf(sacc[0][rr], sacc[1][rr]), fmaxf(sacc[2][rr], sacc[3][rr]));
      cm = fmaxf(cm, __shfl_xor(cm, 1));
      cm = fmaxf(cm, __shfl_xor(cm, 2));
      cm = fmaxf(cm, __shfl_xor(cm, 4));
      cm = fmaxf(cm, __shfl_xor(cm, 8));
      float mn = fmaxf(m_[rr], cm);
      float al = __expf(m_[rr] - mn);
      float ps = 0.f;
#pragma unroll
      for (int ksub = 0; ksub < 4; ++ksub) {
        float pv = __expf(sacc[ksub][rr] - mn);
        p[ksub][rr] = pv;
        ps += pv;
      }
      ps += __shfl_xor(ps, 1);
      ps += __shfl_xor(ps, 2);
      ps += __shfl_xor(ps, 4);
      ps += __shfl_xor(ps, 8);
      l_[rr] = l_[rr] * al + ps;
      m_[rr] = mn;
#pragma unroll
      for (int ds = 0; ds < 4; ++ds) o_[ds][rr] *= al;
    }
#pragma unroll
    for (int ksub = 0; ksub < 4; ++ksub)
#pragma unroll
      for (int rr = 0; rr < 4; ++rr) {
        int r = wid * 16 + ((lane >> 4) << 2) + rr;
        int cb = (ksub * 16 + (lane & 15)) * 2;
        *(ushort*)(pc + r * 128 + (cb ^ ((r & 7) << 4))) = f2bf(p[ksub][rr]);
      }
    __builtin_amdgcn_s_setprio(1);
#pragma unroll
    for (int kk2 = 0; kk2 < 2; ++kk2) {
      int rA = wid * 16 + (lane & 15);
      int c2 = kk2 * 64 + ((lane >> 4) << 4);
      bf16x8 ap = *(bf16x8*)(pc + rA * 128 + (c2 ^ ((rA & 7) << 4)));
#pragma unroll
      for (int ds = 0; ds < 4; ++ds) {
        int rB = ds * 16 + (lane & 15);
        bf16x8 bv = *(bf16x8*)(vc + rB * 128 + (c2 ^ ((rB & 7) << 4)));
        o_[ds] = __builtin_amdgcn_mfma_f32_16x16x32_bf16(ap, bv, o_[ds], 0, 0, 0);
      }
    }
    __builtin_amdgcn_s_setprio(0);
  }
#pragma unroll
  for (int rr = 0; rr < 4; ++rr) {
    float inv = 1.f / l_[rr];
    int q = q0 + wid * 16 + ((lane >> 4) << 2) + rr;
#pragma unroll
    for (int ds = 0; ds < 4; ++ds) {
      int d = ds * 16 + (lane & 15);
      O[((size_t)(b * S_ + q)) * D3_ + h * HD_ + d] = f2bf(o_[ds][rr] * inv);
    }
  }
}

// ---------------- host ----------------
extern "C" void kernel_launch(void* const* d_in, const int* in_sizes, int n_in,
                              void* d_out, int out_size, void* d_ws, size_t ws_size,
                              hipStream_t stream) {
  const float* input_q = (const float*)d_in[0];
  const float* ln_q_w  = (const float*)d_in[1];
  const float* ln_kv_w = (const float*)d_in[2];
  const float* dirty_zq  = (const float*)d_in[15];
  const float* dirty_zkv = (const float*)d_in[16];
  const float* e2de    = (const float*)d_in[17];
  const float* rope_q_f = (const float*)d_in[31];
  const float* rope_k_f = (const float*)d_in[32];
  const float* ln2_w   = (const float*)d_in[34];
  const float* eps_zq  = (const float*)d_in[37];
  const float* eps_zkv = (const float*)d_in[38];

  ushort* wsu = (ushort*)d_ws;
  ushort* wb    = wsu;                        // weights bf16 [0, 12124160)
  ushort* xq_b  = wsu + 12124160;             // [8,1024,768] bf16
  ushort* xkv_b = wsu + 18415616;
  ushort* xqT   = wsu + 37289984;             // [8,768,1024]
  ushort* xkvT  = wsu + 43581440;
  ushort* inT   = wsu + 49872896;
  ushort* t1q   = wsu + 12124160;             // (xq_b/xkv_b dead after transposes)
  ushort* t1kv  = wsu + 15269888;
  ushort* t2b   = wsu + 24707072;             // [32][256][512] -> ends 28901376
  ushort* mv    = wsu + 28901376;             // [32][256][256] -> ends 30998528
  ushort* zqb   = wsu + 30998528;
  ushort* zkvb  = wsu + 31522816;
  ushort* zqT   = wsu + 32047104;
  ushort* zkvT  = wsu + 32571392;             // ends 33095680
  ushort* up    = wsu + 12124160;             // [4][8][1024][256] (t1 dead) -> ends 20512768
  ushort* vzf   = wsu + 20512768;             // [8192,768] -> ends 26804224 (t2b dead)
  ushort* mid   = wsu + 56164352;             // [3][8192][512] -> ends 68747264
  ushort* tkr   = wsu + 37289984;             // (xqT dead)
  ushort* qzf   = wsu + 68747264;
  ushort* kzf   = wsu + 71892992;
  ushort* qrf   = wsu + 75038720;
  ushort* krf   = wsu + 78184448;
  float*  ctq   = (float*)(wsu + 81330176);
  float*  stq   = ctq + 16384;
  float*  ctk   = ctq + 32768;
  float*  stk   = ctq + 49152;
  ushort* qp    = wsu + 12124160;             // (up dead after step 11)
  ushort* kp    = wsu + 43581440;             // (xkvT dead)
  ushort* vp    = wsu + 49872896;             // (inT dead after step 14)
  ushort* ofb   = wsu + 56164352;             // (mid dead)
  float*  xb    = (float*)(wsu + 12124160);   // (qp/vzf dead after attn/packs)
  ushort* ylb   = wsu + 37289984;             // (tkr dead)
  ushort* hm    = wsu + 43581440;             // [8192,3072] (kp/vp/ofb dead)

  const int W_mq = 0,       W_mkv = 524288;
  const int Wq1 = 1048576,  Wv1 = 1441792,  Wk1 = 1835008,  Wkv1 = 2228224;
  const int Wq2 = 2621440,  Wv2 = 2752512,  Wk2 = 2883584,  Wkv2 = 3014656;
  const int W_qzu = 3145728, W_kzu = 3407872, W_vzu = 3670016, W_qr = 3932160;
  const int W_kr = 4194304, W_qzup = 5242880, W_kzup = 5373952, W_vzup = 5505024;
  const int W_qw = 5636096, W_kw = 5832704,  W_vw = 6029312,  W_qrw = 6422528;
  const int W_krw = 6520832, W_ow = 6815744, W_m1 = 7405568,  W_m2 = 9764864;

  // 1) dual LN -> bf16
  ln_dual_b<<<B_ * S_, 256, 0, stream>>>(input_q, ln_q_w, ln_kv_w, xq_b, xkv_b, D1_);

  // 2) transposes to [b, D, S]
  {
    dim3 g(D1_ / 32, S_ / 32, B_);
    trans_b2b<<<g, 256, 0, stream>>>(xq_b, xqT, S_, D1_, (long)S_ * D1_);
    trans_b2b<<<g, 256, 0, stream>>>(xkv_b, xkvT, S_, D1_, (long)S_ * D1_);
    trans_f2b<<<g, 256, 0, stream>>>(input_q, inT, S_, D1_, (long)S_ * D1_);
  }

  // 3) weights -> bf16 + RoPE tables
  {
    ConvTab t;
    const int srcIdx[28] = {3,4,5,6, 7,9,11,13, 8,10,12,14, 18,19,20,21, 22,
                            23,24,25, 26,27, 28, 29, 30, 33, 35, 36};
    const int sz[28] = {262144,262144,262144,262144, 393216,393216,393216,393216,
                        131072,131072,131072,131072, 262144,262144,262144,262144,
                        1048576, 131072,131072,131072, 196608,196608, 393216,
                        98304, 294912, 589824, 2359296, 2359296};
    int off = 0, c4 = 0;
    for (int i = 0; i < 28; ++i) {
      t.src[i] = (const float*)d_in[srcIdx[i]];
      t.off[i] = off;
      t.cum[i] = c4;
      off += sz[i];
      c4 += sz[i] / 4;
    }
    t.cum[28] = c4;
    multi_f2b<<<(c4 + 255) / 256, 256, 0, stream>>>(t, wb, c4);
    rope_tab<<<64, 256, 0, stream>>>(rope_q_f, rope_k_f, ctq, stq, ctk, stk, 16384);
  }

  long sXT = (long)S_ * D1_;

  // 4) grouped seq-compress: z=16
  {
    GrpTab t;
    for (int c = 0; c < 2; ++c)
      for (int b = 0; b < 8; ++b) {
        int z = c * 8 + b;
        t.A[z] = wb + (c == 0 ? W_mq : W_mkv);
        t.Bm[z] = (c == 0 ? xqT : xkvT) + (size_t)b * sXT;
        t.C[z] = (c == 0 ? t1q : t1kv) + (size_t)b * 512 * 768;
      }
    dim3 g(D1_ / 128, 512 / 128, 16);
    gemm_grp<<<g, 256, 0, stream>>>(t, 512, D1_, S_);
  }
  // 5) grouped w1: z=32
  {
    GrpTab t;
    const int wo[4] = {Wq1, Wv1, Wk1, Wkv1};
    for (int c = 0; c < 4; ++c)
      for (int b = 0; b < 8; ++b) {
        int z = c * 8 + b;
        ushort* t1 = (c < 2 ? t1q : t1kv);
        t.A[z] = t1 + (size_t)b * 512 * 768 + (size_t)(c & 1) * 256 * 768;
        t.Bm[z] = wb + wo[c];
        t.C[z] = t2b + (size_t)z * 256 * 512;
      }
    dim3 g(D2_ / 128, 256 / 128, 32);
    gemm_grp<<<g, 256, 0, stream>>>(t, 256, D2_, D1_);
  }
  // 6) grouped w2: z=32
  {
    GrpTab t;
    const int wo[4] = {Wq2, Wv2, Wk2, Wkv2};
    for (int c = 0; c < 4; ++c)
      for (int b = 0; b < 8; ++b) {
        int z = c * 8 + b;
        t.A[z] = t2b + (size_t)z * 256 * 512;
        t.Bm[z] = wb + wo[c];
        t.C[z] = mv + (size_t)z * 256 * 256;
      }
    dim3 g(MVH_ / 128, 256 / 128, 32);
    gemm_grp<<<g, 256, 0, stream>>>(t, 256, MVH_, D2_);
  }
  // 7) reparam
  z_combine_b<<<(B_ * SR_ * MVH_) / 256, 256, 0, stream>>>(mv, mv + 8 * 65536,
      eps_zq, dirty_zq, e2de, zqb, B_ * SR_ * MVH_, SR_ * MVH_);
  z_combine_b<<<(B_ * SR_ * MVH_) / 256, 256, 0, stream>>>(mv + 16 * 65536,
      mv + 24 * 65536, eps_zkv, dirty_zkv, e2de, zkvb, B_ * SR_ * MVH_, SR_ * MVH_);
  // 8) z transposes
  {
    dim3 g(MVH_ / 32, SR_ / 32, B_);
    trans_b2b<<<g, 256, 0, stream>>>(zqb, zqT, SR_, MVH_, (long)SR_ * MVH_);
    trans_b2b<<<g, 256, 0, stream>>>(zkvb, zkvT, SR_, MVH_, (long)SR_ * MVH_);
  }
  // 9) grouped upsample-1: z=32
  {
    GrpTab t;
    const int wo[4] = {W_qzu, W_kzu, W_vzu, W_qr};
    for (int c = 0; c < 4; ++c)
      for (int b = 0; b < 8; ++b) {
        int z = c * 8 + b;
        t.A[z] = wb + wo[c];
        t.Bm[z] = ((c == 0 || c == 3) ? zqT : zkvT) + (size_t)b * 65536;
        t.C[z] = up + (size_t)z * 1024 * 256;
      }
    dim3 g(MVH_ / 128, SN_ / 128, 32);
    gemm_grp<<<g, 256, 0, stream>>>(t, SN_, MVH_, SR_);
  }
  // 10) grouped upsample-2 (qz,kz,vz): z=3
  {
    GrpTab t;
    const int wo[3] = {W_qzup, W_kzup, W_vzup};
    for (int c = 0; c < 3; ++c) {
      t.A[c] = up + (size_t)c * 8 * 1024 * 256;
      t.Bm[c] = wb + wo[c];
      t.C[c] = mid + (size_t)c * 8192 * 512;
    }
    dim3 g(D2_ / 128, (B_ * SN_) / 128, 3);
    gemm_grp<<<g, 256, 0, stream>>>(t, B_ * SN_, D2_, MVH_);
  }
  // 11) qr stage-2
  {
    dim3 g(384 / 128, (B_ * SN_) / 128, 1);
    gemm_bf16<0><<<g, 256, 0, stream>>>(up + (size_t)3 * 8 * 1024 * 256, 0,
        wb + W_qrw, 0, nullptr, qrf, 0, B_ * SN_, 384, MVH_);
  }
  // 12) grouped stage-3 (q_w, k_w): z=2
  {
    GrpTab t;
    t.A[0] = mid;                      t.Bm[0] = wb + W_qw; t.C[0] = qzf;
    t.A[1] = mid + (size_t)8192 * 512; t.Bm[1] = wb + W_kw; t.C[1] = kzf;
    dim3 g(384 / 128, (B_ * SN_) / 128, 2);
    gemm_grp<<<g, 256, 0, stream>>>(t, B_ * SN_, 384, D2_);
  }
  // 13) v_w
  {
    dim3 g(D3_ / 128, (B_ * SN_) / 128, 1);
    gemm_bf16<0><<<g, 256, 0, stream>>>(mid + (size_t)2 * 8192 * 512, 0,
        wb + W_vw, 0, nullptr, vzf, 0, B_ * SN_, D3_, D2_);
  }
  // 14) kr stage-1 (strided batch)
  {
    dim3 g(D1_ / 128, SN_ / 128, B_);
    gemm_bf16<0><<<g, 256, 0, stream>>>(wb + W_kr, 0, inT, sXT, nullptr, tkr,
        (long)SN_ * D1_, SN_, D1_, S_);
  }
  // 15) kr stage-2
  {
    dim3 g(384 / 128, (B_ * SN_) / 128, 1);
    gemm_bf16<0><<<g, 256, 0, stream>>>(tkr, 0, wb + W_krw, 0, nullptr, krf, 0,
        B_ * SN_, 384, D1_);
  }

  // 16) fused pack (q, k, v sections)
  int nblk = (B_ * H_ * S_ * HD_) / 8 / 256;   // 3072 blocks per section
  pack_all<<<3 * nblk, 256, 0, stream>>>(qzf, qrf, ctq, stq, qp,
                                         kzf, krf, ctk, stk, kp, vzf, vp, nblk);

  // 17) attention (QBLK=64)
  {
    dim3 g(S_ / 64, B_ * H_);
    attn_mfma<<<g, 256, 0, stream>>>(qp, kp, vp, ofb);
  }

  // 18) epilogue
  {
    dim3 g(D3_ / 128, (B_ * SN_) / 128);
    gemm_bf16<1><<<g, 256, 0, stream>>>(ofb, 0, wb + W_ow, 0, input_q, xb, 0,
                                        B_ * SN_, D3_, D3_);
  }
  ln_b<<<B_ * SN_, 256, 0, stream>>>(xb, ln2_w, ylb, D3_);
  {
    dim3 g(MLP_ / 128, (B_ * SN_) / 128);
    gemm_bf16<2><<<g, 256, 0, stream>>>(ylb, 0, wb + W_m1, 0, nullptr, hm, 0,
                                        B_ * SN_, MLP_, D3_);
  }
  {
    dim3 g(D3_ / 128, (B_ * SN_) / 128);
    gemm_bf16<1><<<g, 256, 0, stream>>>(hm, 0, wb + W_m2, 0, xb, (float*)d_out, 0,
                                        B_ * SN_, D3_, MLP_);
  }
}